// Round 1
// baseline (303.222 us; speedup 1.0000x reference)
//
#include <hip/hip_runtime.h>
#include <math.h>

#define NF 64
#define NN 4096
#define MM 32
#define LOG2F_ 0.69314718055994530942f

// shifted softplus: log(1+exp(x)) - log(2); ssp(0) == 0 exactly
__device__ __forceinline__ float ssp(float x) {
    float sp = (x > 20.0f) ? x : log1pf(expf(x));
    return sp - LOG2F_;
}

// Kernel 1: pre = ielin(feat_in, w_pre0, w_pre1)  -> (N, 256) in workspace
__global__ __launch_bounds__(256) void pre_kernel(
    const float* __restrict__ feat, const float* __restrict__ w0,
    const float* __restrict__ w1, float* __restrict__ pre)
{
    int i = blockIdx.x;
    int t = threadIdx.x;
    __shared__ float s_feat[256];
    s_feat[t] = feat[i * 256 + t];
    __syncthreads();
    float acc = 0.f;
    if (t < 64) {
        #pragma unroll 8
        for (int c = 0; c < 64; ++c) acc = fmaf(s_feat[c], w0[c * 64 + t], acc);
    } else {
        int m = (t >> 6) - 1, d = t & 63;
        const float* fsrc = &s_feat[64 + m * 64];
        #pragma unroll 8
        for (int c = 0; c < 64; ++c) acc = fmaf(fsrc[c], w1[c * 64 + d], acc);
    }
    pre[i * 256 + t] = acc;
}

// Kernel 2: per-node block. 4 waves x 8 edges; lane == channel.
// Aggregates coupler outputs over masked edges (coupling is linear in the
// filter, so mask & aggregation commute with the ielin_a matmul), then does
// the per-node finish: ielin_a -> gate -> ielin_b -> residual.
__global__ __launch_bounds__(256) void edge_kernel(
    const float* __restrict__ xyz, const float* __restrict__ feat,
    const float* __restrict__ pre,
    const float* __restrict__ w_f1, const float* __restrict__ w_f2,
    const float* __restrict__ w_a0, const float* __restrict__ w_a1,
    const float* __restrict__ w_b0, const float* __restrict__ w_b1,
    const int* __restrict__ src_idx, const int* __restrict__ edge_mask,
    float* __restrict__ out)
{
    int i = blockIdx.x;
    int t = threadIdx.x;
    int lane = t & 63;
    int wave = t >> 6;

    __shared__ float s_wf1[16 * 64];
    __shared__ float s_wf2[64 * 64];
    __shared__ float s_agg[704];   // aggregated coup, reference layout
    __shared__ float s_cout[256];
    __shared__ float s_gated[256];

    for (int k = t; k < 16 * 64; k += 256) s_wf1[k] = w_f1[k];
    for (int k = t; k < 64 * 64; k += 256) s_wf2[k] = w_f2[k];
    for (int k = t; k < 704; k += 256) s_agg[k] = 0.f;

    float xi0 = xyz[i * 3 + 0], xi1 = xyz[i * 3 + 1], xi2 = xyz[i * 3 + 2];

    // per-lane (=channel) coupling accumulators
    float acc0a = 0.f, acc0b = 0.f;
    float accP01[3] = {0.f, 0.f, 0.f};
    float accP10[3] = {0.f, 0.f, 0.f};
    float accP11[3] = {0.f, 0.f, 0.f};

    __syncthreads();

    for (int e = 0; e < 8; ++e) {
        int m = wave * 8 + e;
        int j = src_idx[i * MM + m];
        float msk = (float)edge_mask[i * MM + m];

        float r0 = xyz[j * 3 + 0] - xi0;
        float r1 = xyz[j * 3 + 1] - xi1;
        float r2 = xyz[j * 3 + 2] - xi2;
        float d2 = r0 * r0 + r1 * r1 + r2 * r2;
        float d = sqrtf(d2);
        float inv_d = 1.0f / d;
        float x = d * 0.2f;
        float env = 0.f;
        if (x < 1.f) {
            float x3 = x * x * x;
            env = 1.f - 10.f * x3 + 15.f * x3 * x - 6.f * x3 * x * x;
        }
        float scale = env * inv_d;

        // rbf: lane k<16 computes sin(x*k)*env/d, broadcast by shuffle
        float sv = (lane < 16) ? sinf(x * (float)lane) * scale : 0.f;
        float hacc = 0.f;
        #pragma unroll
        for (int k = 0; k < 16; ++k) {
            float rk = __shfl(sv, k, 64);
            hacc = fmaf(rk, s_wf1[k * 64 + lane], hacc);
        }
        float h = ssp(hacc);
        float facc = 0.f;
        #pragma unroll 8
        for (int k = 0; k < 64; ++k) {
            float hk = __shfl(h, k, 64);
            facc = fmaf(hk, s_wf2[k * 64 + lane], facc);
        }
        float f = facc * msk;  // mask folds linearly into the filter

        // gather pre[j] (coalesced 256B per segment)
        const float* pj = &pre[j * 256];
        float a0  = pj[lane];
        float a1y = pj[64 + lane];
        float a1z = pj[128 + lane];
        float a1x = pj[192 + lane];

        float ry = r1 * inv_d, rz = r2 * inv_d, rx = r0 * inv_d;

        float a0f = a0 * f;
        acc0a += a0f;
        acc0b = fmaf(f, a1y * ry + a1z * rz + a1x * rx, acc0b);
        // p01[m] = a0 * f * rsh[m],  rsh m-order (y,z,x)
        accP01[0] = fmaf(a0f, ry, accP01[0]);
        accP01[1] = fmaf(a0f, rz, accP01[1]);
        accP01[2] = fmaf(a0f, rx, accP01[2]);
        // p10[m] = a1[m] * f
        accP10[0] = fmaf(a1y, f, accP10[0]);
        accP10[1] = fmaf(a1z, f, accP10[1]);
        accP10[2] = fmaf(a1x, f, accP10[2]);
        // p11 = cross in cartesian, back to rsh order (cy,cz,cx)
        float cx = (a1y * rz - a1z * ry) * f;
        float cy = (a1z * rx - a1x * rz) * f;
        float cz = (a1x * ry - a1y * rx) * f;
        accP11[0] += cy;
        accP11[1] += cz;
        accP11[2] += cx;
    }

    // cross-wave reduction into s_agg (reference coup layout)
    atomicAdd(&s_agg[lane], acc0a);
    atomicAdd(&s_agg[64 + lane], acc0b);
    #pragma unroll
    for (int m = 0; m < 3; ++m) {
        atomicAdd(&s_agg[128 + m * 192 + lane], accP01[m]);
        atomicAdd(&s_agg[128 + m * 192 + 64 + lane], accP10[m]);
        atomicAdd(&s_agg[128 + m * 192 + 128 + lane], accP11[m]);
    }
    __syncthreads();

    // cout = ielin(agg, w_a0, w_a1)
    {
        float acc = 0.f;
        if (t < 64) {
            #pragma unroll 8
            for (int c = 0; c < 128; ++c)
                acc = fmaf(s_agg[c], w_a0[c * 64 + t], acc);
        } else {
            int m = (t >> 6) - 1, d = t & 63;
            const float* src = &s_agg[128 + m * 192];
            #pragma unroll 8
            for (int c = 0; c < 192; ++c)
                acc = fmaf(src[c], w_a1[c * 64 + d], acc);
        }
        s_cout[t] = acc;
    }
    __syncthreads();

    // gate
    {
        int d = t & 63;
        float v = s_cout[t];
        float g;
        if (t < 64) {
            g = ssp(v);
        } else {
            float c0 = s_cout[64 + d], c1 = s_cout[128 + d], c2 = s_cout[192 + d];
            float n = sqrtf(fmaf(c0, c0, fmaf(c1, c1, fmaf(c2, c2, 1e-12f))));
            g = ssp(n);
        }
        s_gated[t] = v * g;
    }
    __syncthreads();

    // out = feat_in + ielin(gated, w_b0, w_b1)
    {
        float acc = 0.f;
        if (t < 64) {
            #pragma unroll 8
            for (int c = 0; c < 64; ++c)
                acc = fmaf(s_gated[c], w_b0[c * 64 + t], acc);
        } else {
            int m = (t >> 6) - 1, d = t & 63;
            const float* src = &s_gated[64 + m * 64];
            #pragma unroll 8
            for (int c = 0; c < 64; ++c)
                acc = fmaf(src[c], w_b1[c * 64 + d], acc);
        }
        out[i * 256 + t] = feat[i * 256 + t] + acc;
    }
}

extern "C" void kernel_launch(void* const* d_in, const int* in_sizes, int n_in,
                              void* d_out, int out_size, void* d_ws, size_t ws_size,
                              hipStream_t stream) {
    const float* xyz     = (const float*)d_in[0];
    const float* feat    = (const float*)d_in[1];
    const float* w_f1    = (const float*)d_in[2];
    const float* w_f2    = (const float*)d_in[3];
    const float* w_pre0  = (const float*)d_in[4];
    const float* w_pre1  = (const float*)d_in[5];
    const float* w_a0    = (const float*)d_in[6];
    const float* w_a1    = (const float*)d_in[7];
    const float* w_b0    = (const float*)d_in[8];
    const float* w_b1    = (const float*)d_in[9];
    const int* src_idx   = (const int*)d_in[10];
    const int* edge_mask = (const int*)d_in[11];
    float* out = (float*)d_out;
    float* pre = (float*)d_ws;  // N*256 floats = 4 MB

    pre_kernel<<<NN, 256, 0, stream>>>(feat, w_pre0, w_pre1, pre);
    edge_kernel<<<NN, 256, 0, stream>>>(xyz, feat, pre, w_f1, w_f2,
                                        w_a0, w_a1, w_b0, w_b1,
                                        src_idx, edge_mask, out);
}

// Round 2
// 198.178 us; speedup vs baseline: 1.5301x; 1.5301x over previous
//
#include <hip/hip_runtime.h>
#include <math.h>

#define NF 64
#define NN 4096
#define MM 32
#define LOG2F_ 0.69314718055994530942f

typedef __attribute__((ext_vector_type(8))) short short8;
typedef __attribute__((ext_vector_type(4))) float f32x4;

// shifted softplus: log(1+exp(x)) - log(2); ssp(0) == 0 exactly
__device__ __forceinline__ float ssp(float x) {
    float sp = (x > 20.0f) ? x : log1pf(expf(x));
    return sp - LOG2F_;
}

// float -> bf16 bits with round-to-nearest-even
__device__ __forceinline__ short f2bf(float x) {
    unsigned u = __float_as_uint(x);
    unsigned r = (u + 0x7FFFu + ((u >> 16) & 1u)) >> 16;
    return (short)r;
}

// Setup: w1t[n][k] (64x32, k>=16 zero-padded) and w2t[n][k] (64x64), bf16,
// B^T layout so B-fragments are contiguous-in-k ds_read_b128s.
__global__ __launch_bounds__(256) void setup_kernel(
    const float* __restrict__ w_f1, const float* __restrict__ w_f2,
    short* __restrict__ w1t, short* __restrict__ w2t)
{
    int t0 = blockIdx.x * 256 + threadIdx.x;
    int stride = gridDim.x * 256;
    for (int idx = t0; idx < 64 * 32; idx += stride) {
        int n = idx >> 5, k = idx & 31;
        w1t[idx] = (k < 16) ? f2bf(w_f1[k * 64 + n]) : (short)0;
    }
    for (int idx = t0; idx < 64 * 64; idx += stride) {
        int n = idx >> 6, k = idx & 63;
        w2t[idx] = f2bf(w_f2[k * 64 + n]);
    }
}

// pre = ielin(feat_in, w_pre0, w_pre1): 8 nodes per block, weight column in
// registers (64 VGPRs), double-buffered feat tile, float4 LDS broadcasts.
__global__ __launch_bounds__(256) void pre_kernel(
    const float* __restrict__ feat, const float* __restrict__ w0,
    const float* __restrict__ w1, float* __restrict__ pre)
{
    int t = threadIdx.x;
    int base = blockIdx.x * 8;
    int lane2 = t & 63;
    int sel = t >> 6;  // 0: l0 path; 1..3: l1 m index + 1

    float wcol[64];
    const float* wsrc = (t < 64) ? w0 : w1;
    #pragma unroll
    for (int c = 0; c < 64; ++c) wcol[c] = wsrc[c * 64 + lane2];

    __shared__ __align__(16) float s_feat[2][256];
    s_feat[0][t] = feat[base * 256 + t];

    for (int n = 0; n < 8; ++n) {
        __syncthreads();
        if (n < 7) s_feat[(n + 1) & 1][t] = feat[(base + n + 1) * 256 + t];
        const float* fs = (t < 64) ? &s_feat[n & 1][0]
                                   : &s_feat[n & 1][64 + (sel - 1) * 64];
        const float4* f4 = (const float4*)fs;
        float acc = 0.f;
        #pragma unroll
        for (int c4 = 0; c4 < 16; ++c4) {
            float4 v = f4[c4];
            acc = fmaf(v.x, wcol[c4 * 4 + 0], acc);
            acc = fmaf(v.y, wcol[c4 * 4 + 1], acc);
            acc = fmaf(v.z, wcol[c4 * 4 + 2], acc);
            acc = fmaf(v.w, wcol[c4 * 4 + 3], acc);
        }
        pre[(base + n) * 256 + t] = acc;
    }
}

// Per-node block: rbf -> MFMA(bf16) radial MLP -> coupling -> aggregate ->
// ielin_a -> gate -> ielin_b -> residual.
__global__ __launch_bounds__(256) void edge_kernel(
    const float* __restrict__ xyz, const float* __restrict__ feat,
    const float* __restrict__ pre,
    const short* __restrict__ w1t_g, const short* __restrict__ w2t_g,
    const float* __restrict__ w_a0, const float* __restrict__ w_a1,
    const float* __restrict__ w_b0, const float* __restrict__ w_b1,
    const int* __restrict__ src_idx, const int* __restrict__ edge_mask,
    float* __restrict__ out)
{
    int i = blockIdx.x;
    int t = threadIdx.x;
    int lane = t & 63;
    int wave = t >> 6;
    int q = lane >> 4;      // quad within wave
    int nn = lane & 15;     // position within 16-wide tile

    // bf16 tiles: strides padded to avoid LDS bank conflicts, 16B-aligned rows
    __shared__ __align__(16) short s_w1t[64 * 40];  // w1^T, K padded to 32
    __shared__ __align__(16) short s_w2t[64 * 72];  // w2^T
    __shared__ __align__(16) short s_rbf[32 * 40];  // rbf, A layout, K pad 32
    __shared__ __align__(16) short s_h[32 * 72];    // hidden, A layout
    __shared__ __align__(16) float s_f[32 * 68];    // filters fp32
    __shared__ __align__(16) float s_geo[32 * 4];   // {ry, rz, rx, mask}
    __shared__ float s_xs[32 * 2];                  // {x, env/d}
    __shared__ int s_ji[32];
    __shared__ __align__(16) float s_agg[704];
    __shared__ __align__(16) float s_cout[256];
    __shared__ __align__(16) float s_gated[256];

    // ---- stage weights (b128 copies), zero s_agg & s_rbf ----
    {
        int4 v1 = ((const int4*)w1t_g)[t];          // 256 chunks of 8 bf16
        *(int4*)&s_w1t[(t >> 2) * 40 + (t & 3) * 8] = v1;
        #pragma unroll
        for (int rep = 0; rep < 2; ++rep) {
            int c = t + rep * 256;
            int4 v2 = ((const int4*)w2t_g)[c];      // 512 chunks
            *(int4*)&s_w2t[(c >> 3) * 72 + (c & 7) * 8] = v2;
        }
        for (int k = t; k < 1280; k += 256) s_rbf[k] = 0;
        for (int k = t; k < 704; k += 256) s_agg[k] = 0.f;
    }

    // ---- P1a: per-edge geometry (threads 0..31) ----
    if (t < 32) {
        int e = t;
        int j = src_idx[i * MM + e];
        float msk = (float)edge_mask[i * MM + e];
        float xi0 = xyz[i * 3 + 0], xi1 = xyz[i * 3 + 1], xi2 = xyz[i * 3 + 2];
        float r0 = xyz[j * 3 + 0] - xi0;
        float r1 = xyz[j * 3 + 1] - xi1;
        float r2 = xyz[j * 3 + 2] - xi2;
        float d = sqrtf(r0 * r0 + r1 * r1 + r2 * r2);
        float inv_d = 1.0f / d;
        float x = d * 0.2f;
        float env = 0.f;
        if (x < 1.f) {
            float x3 = x * x * x;
            env = 1.f - 10.f * x3 + 15.f * x3 * x - 6.f * x3 * x * x;
        }
        s_geo[e * 4 + 0] = r1 * inv_d;   // y
        s_geo[e * 4 + 1] = r2 * inv_d;   // z
        s_geo[e * 4 + 2] = r0 * inv_d;   // x
        s_geo[e * 4 + 3] = msk;
        s_xs[e * 2 + 0] = x;
        s_xs[e * 2 + 1] = env * inv_d;
        s_ji[e] = j;
    }
    __syncthreads();

    // ---- P1b: rbf values (512 sins, 2 per thread) ----
    #pragma unroll
    for (int rep = 0; rep < 2; ++rep) {
        int idx = t + rep * 256;
        int e = idx >> 4, k = idx & 15;
        float x = s_xs[e * 2 + 0], sc = s_xs[e * 2 + 1];
        s_rbf[e * 40 + k] = f2bf(sinf(x * (float)k) * sc);
    }
    __syncthreads();

    // ---- P2: h = ssp(rbf @ w1) via MFMA; wave = 16-col tile ----
    {
        f32x4 z = {0.f, 0.f, 0.f, 0.f};
        #pragma unroll
        for (int mt = 0; mt < 2; ++mt) {
            short8 a = *(const short8*)&s_rbf[(16 * mt + nn) * 40 + q * 8];
            short8 b = *(const short8*)&s_w1t[(16 * wave + nn) * 40 + q * 8];
            f32x4 h = __builtin_amdgcn_mfma_f32_16x16x32_bf16(a, b, z, 0, 0, 0);
            #pragma unroll
            for (int r = 0; r < 4; ++r) {
                int e = 16 * mt + 4 * q + r;
                s_h[e * 72 + 16 * wave + nn] = f2bf(ssp(h[r]));
            }
        }
    }
    __syncthreads();

    // ---- P3: fr = h @ w2 via MFMA (K=64 -> 2 chunks) ----
    {
        f32x4 facc[2];
        facc[0] = (f32x4){0.f, 0.f, 0.f, 0.f};
        facc[1] = (f32x4){0.f, 0.f, 0.f, 0.f};
        #pragma unroll
        for (int kc = 0; kc < 2; ++kc) {
            short8 b = *(const short8*)&s_w2t[(16 * wave + nn) * 72 + kc * 32 + q * 8];
            #pragma unroll
            for (int mt = 0; mt < 2; ++mt) {
                short8 a = *(const short8*)&s_h[(16 * mt + nn) * 72 + kc * 32 + q * 8];
                facc[mt] = __builtin_amdgcn_mfma_f32_16x16x32_bf16(a, b, facc[mt], 0, 0, 0);
            }
        }
        #pragma unroll
        for (int mt = 0; mt < 2; ++mt)
            #pragma unroll
            for (int r = 0; r < 4; ++r) {
                int e = 16 * mt + 4 * q + r;
                s_f[e * 68 + 16 * wave + nn] = facc[mt][r];
            }
    }
    __syncthreads();

    // ---- P4: coupling + aggregation (lane == channel, 8 edges per wave) ----
    {
        float acc0a = 0.f, acc0b = 0.f;
        float accP01[3] = {0.f, 0.f, 0.f};
        float accP10[3] = {0.f, 0.f, 0.f};
        float accP11[3] = {0.f, 0.f, 0.f};

        #pragma unroll 2
        for (int ee = 0; ee < 8; ++ee) {
            int e = wave * 8 + ee;
            float4 g = *(const float4*)&s_geo[e * 4];
            float ry = g.x, rz = g.y, rx = g.z, msk = g.w;
            int j = s_ji[e];
            float f = s_f[e * 68 + lane] * msk;

            const float* pj = &pre[j * 256];
            float a0  = pj[lane];
            float a1y = pj[64 + lane];
            float a1z = pj[128 + lane];
            float a1x = pj[192 + lane];

            float a0f = a0 * f;
            acc0a += a0f;
            acc0b = fmaf(f, a1y * ry + a1z * rz + a1x * rx, acc0b);
            accP01[0] = fmaf(a0f, ry, accP01[0]);
            accP01[1] = fmaf(a0f, rz, accP01[1]);
            accP01[2] = fmaf(a0f, rx, accP01[2]);
            accP10[0] = fmaf(a1y, f, accP10[0]);
            accP10[1] = fmaf(a1z, f, accP10[1]);
            accP10[2] = fmaf(a1x, f, accP10[2]);
            float cx = (a1y * rz - a1z * ry) * f;
            float cy = (a1z * rx - a1x * rz) * f;
            float cz = (a1x * ry - a1y * rx) * f;
            accP11[0] += cy;
            accP11[1] += cz;
            accP11[2] += cx;
        }

        atomicAdd(&s_agg[lane], acc0a);
        atomicAdd(&s_agg[64 + lane], acc0b);
        #pragma unroll
        for (int m = 0; m < 3; ++m) {
            atomicAdd(&s_agg[128 + m * 192 + lane], accP01[m]);
            atomicAdd(&s_agg[128 + m * 192 + 64 + lane], accP10[m]);
            atomicAdd(&s_agg[128 + m * 192 + 128 + lane], accP11[m]);
        }
    }
    __syncthreads();

    // ---- P5a: cout = ielin(agg, w_a0, w_a1) ----
    {
        float acc = 0.f;
        if (t < 64) {
            const float4* ag = (const float4*)s_agg;
            #pragma unroll 8
            for (int c4 = 0; c4 < 32; ++c4) {
                float4 v = ag[c4];
                int c = c4 * 4;
                acc = fmaf(v.x, w_a0[(c + 0) * 64 + t], acc);
                acc = fmaf(v.y, w_a0[(c + 1) * 64 + t], acc);
                acc = fmaf(v.z, w_a0[(c + 2) * 64 + t], acc);
                acc = fmaf(v.w, w_a0[(c + 3) * 64 + t], acc);
            }
        } else {
            int m = (t >> 6) - 1, d = t & 63;
            const float4* ag = (const float4*)&s_agg[128 + m * 192];
            #pragma unroll 8
            for (int c4 = 0; c4 < 48; ++c4) {
                float4 v = ag[c4];
                int c = c4 * 4;
                acc = fmaf(v.x, w_a1[(c + 0) * 64 + d], acc);
                acc = fmaf(v.y, w_a1[(c + 1) * 64 + d], acc);
                acc = fmaf(v.z, w_a1[(c + 2) * 64 + d], acc);
                acc = fmaf(v.w, w_a1[(c + 3) * 64 + d], acc);
            }
        }
        s_cout[t] = acc;
    }
    __syncthreads();

    // ---- gate ----
    {
        int d = t & 63;
        float v = s_cout[t];
        float g;
        if (t < 64) {
            g = ssp(v);
        } else {
            float c0 = s_cout[64 + d], c1 = s_cout[128 + d], c2 = s_cout[192 + d];
            float n = sqrtf(fmaf(c0, c0, fmaf(c1, c1, fmaf(c2, c2, 1e-12f))));
            g = ssp(n);
        }
        s_gated[t] = v * g;
    }
    __syncthreads();

    // ---- P5b: out = feat_in + ielin(gated, w_b0, w_b1) ----
    {
        float acc = 0.f;
        const float* wsel;
        const float4* gs;
        int d;
        if (t < 64) {
            wsel = w_b0; d = t;
            gs = (const float4*)&s_gated[0];
        } else {
            int m = (t >> 6) - 1; d = t & 63;
            wsel = w_b1;
            gs = (const float4*)&s_gated[64 + m * 64];
        }
        #pragma unroll 4
        for (int c4 = 0; c4 < 16; ++c4) {
            float4 v = gs[c4];
            int c = c4 * 4;
            acc = fmaf(v.x, wsel[(c + 0) * 64 + d], acc);
            acc = fmaf(v.y, wsel[(c + 1) * 64 + d], acc);
            acc = fmaf(v.z, wsel[(c + 2) * 64 + d], acc);
            acc = fmaf(v.w, wsel[(c + 3) * 64 + d], acc);
        }
        out[i * 256 + t] = feat[i * 256 + t] + acc;
    }
}

extern "C" void kernel_launch(void* const* d_in, const int* in_sizes, int n_in,
                              void* d_out, int out_size, void* d_ws, size_t ws_size,
                              hipStream_t stream) {
    const float* xyz     = (const float*)d_in[0];
    const float* feat    = (const float*)d_in[1];
    const float* w_f1    = (const float*)d_in[2];
    const float* w_f2    = (const float*)d_in[3];
    const float* w_pre0  = (const float*)d_in[4];
    const float* w_pre1  = (const float*)d_in[5];
    const float* w_a0    = (const float*)d_in[6];
    const float* w_a1    = (const float*)d_in[7];
    const float* w_b0    = (const float*)d_in[8];
    const float* w_b1    = (const float*)d_in[9];
    const int* src_idx   = (const int*)d_in[10];
    const int* edge_mask = (const int*)d_in[11];
    float* out = (float*)d_out;

    float* pre   = (float*)d_ws;                          // 4 MB
    short* w1t_g = (short*)((char*)d_ws + (size_t)4194304);  // 4 KB
    short* w2t_g = w1t_g + 64 * 32;                          // 8 KB

    setup_kernel<<<8, 256, 0, stream>>>(w_f1, w_f2, w1t_g, w2t_g);
    pre_kernel<<<NN / 8, 256, 0, stream>>>(feat, w_pre0, w_pre1, pre);
    edge_kernel<<<NN, 256, 0, stream>>>(xyz, feat, pre, w1t_g, w2t_g,
                                        w_a0, w_a1, w_b0, w_b1,
                                        src_idx, edge_mask, out);
}

// Round 3
// 174.921 us; speedup vs baseline: 1.7335x; 1.1330x over previous
//
#include <hip/hip_runtime.h>
#include <math.h>

#define NN 4096
#define MM 32
#define LOG2F_ 0.69314718055994530942f

typedef __attribute__((ext_vector_type(8))) short short8;
typedef __attribute__((ext_vector_type(4))) float f32x4;

// shifted softplus: log(1+exp(x)) - log(2); ssp(0) == 0 exactly
__device__ __forceinline__ float ssp(float x) {
    float sp = (x > 20.0f) ? x : log1pf(expf(x));
    return sp - LOG2F_;
}

// float -> bf16 bits, round-to-nearest-even
__device__ __forceinline__ short f2bf(float x) {
    unsigned u = __float_as_uint(x);
    unsigned r = (u + 0x7FFFu + ((u >> 16) & 1u)) >> 16;
    return (short)r;
}

// Setup: w1t[n][k] (64x32 bf16, k>=16 zero) and w2t[n][k] (64x64 bf16).
// B^T layout: MFMA B-fragments become contiguous 16B register loads.
__global__ __launch_bounds__(256) void setup_kernel(
    const float* __restrict__ w_f1, const float* __restrict__ w_f2,
    short* __restrict__ w1t, short* __restrict__ w2t)
{
    int t0 = blockIdx.x * 256 + threadIdx.x;
    int stride = gridDim.x * 256;
    for (int idx = t0; idx < 64 * 32; idx += stride) {
        int n = idx >> 5, k = idx & 31;
        w1t[idx] = (k < 16) ? f2bf(w_f1[k * 64 + n]) : (short)0;
    }
    for (int idx = t0; idx < 64 * 64; idx += stride) {
        int n = idx >> 6, k = idx & 63;
        w2t[idx] = f2bf(w_f2[k * 64 + n]);
    }
}

// K1: pre_t[node][ch*4 + p], p = {l0, m0(y), m1(z), m2(x)} -> float4 per
// (node, channel): the edge gather becomes one dwordx4. 8 nodes/block;
// weight column held in 64 VGPRs, reused across the 8 nodes.
__global__ __launch_bounds__(256) void pre_kernel(
    const float* __restrict__ feat, const float* __restrict__ w0,
    const float* __restrict__ w1, float* __restrict__ pre_t)
{
    int t = threadIdx.x;
    int base = blockIdx.x * 8;
    int ch = t >> 2, p = t & 3;

    const float* wsrc = (p == 0) ? w0 : w1;
    float wcol[64];
    #pragma unroll
    for (int c = 0; c < 64; ++c) wcol[c] = wsrc[c * 64 + ch];

    __shared__ __align__(16) float s_feat[8][256];
    {
        const float4* src = (const float4*)(feat + (size_t)base * 256);
        float4* dst = (float4*)&s_feat[0][0];
        dst[t] = src[t];
        dst[t + 256] = src[t + 256];
    }
    __syncthreads();

    int aoff = (p == 0) ? 0 : 64 + (p - 1) * 64;
    for (int n = 0; n < 8; ++n) {
        const float4* f4 = (const float4*)&s_feat[n][aoff];
        float acc = 0.f;
        #pragma unroll
        for (int c4 = 0; c4 < 16; ++c4) {
            float4 v = f4[c4];
            acc = fmaf(v.x, wcol[c4 * 4 + 0], acc);
            acc = fmaf(v.y, wcol[c4 * 4 + 1], acc);
            acc = fmaf(v.z, wcol[c4 * 4 + 2], acc);
            acc = fmaf(v.w, wcol[c4 * 4 + 3], acc);
        }
        pre_t[(size_t)(base + n) * 256 + t] = acc;
    }
}

// K2: 2 nodes/block. rbf -> MFMA radial MLP -> coupling w/ float4 gather ->
// per-node agg (704 floats) written to workspace. Weights fragments live in
// registers, loaded straight from the transposed global arrays.
__global__ __launch_bounds__(256) void edge_kernel(
    const float* __restrict__ xyz, const float* __restrict__ pre_t,
    const short* __restrict__ w1t_g, const short* __restrict__ w2t_g,
    const int* __restrict__ src_idx, const int* __restrict__ edge_mask,
    float* __restrict__ agg_g)
{
    int bi = blockIdx.x;           // 2048 blocks x 2 nodes
    int i0 = bi * 2;
    int t = threadIdx.x;
    int lane = t & 63;
    int wave = t >> 6;
    int q = lane >> 4;
    int nn = lane & 15;

    __shared__ __align__(16) short s_rbf[64 * 40];  // A tiles, K pad to 32
    __shared__ __align__(16) short s_h[64 * 72];
    __shared__ __align__(16) float s_f[64 * 68];
    __shared__ __align__(16) float s_geo[64 * 4];   // {ry, rz, rx, mask}
    __shared__ float s_xs[64 * 2];                  // {x, env/d}
    __shared__ int   s_ji[64];
    __shared__ __align__(16) float s_agg[2 * 704];

    // B-fragments straight into registers (L2-hot, coalesced-ish 16B chunks)
    short8 b1 = *(const short8*)&w1t_g[(16 * wave + nn) * 32 + q * 8];
    short8 b2_0 = *(const short8*)&w2t_g[(16 * wave + nn) * 64 + q * 8];
    short8 b2_1 = *(const short8*)&w2t_g[(16 * wave + nn) * 64 + 32 + q * 8];

    for (int k = t; k < 1408; k += 256) s_agg[k] = 0.f;
    for (int idx = t; idx < 1024; idx += 256) {      // zero K-pad cols 16..31
        int e = idx >> 4, k = 16 + (idx & 15);
        s_rbf[e * 40 + k] = 0;
    }

    if (t < 64) {
        int node = t >> 5, e = t & 31;
        int i = i0 + node;
        int j = src_idx[i * MM + e];
        float msk = (float)edge_mask[i * MM + e];
        float r0 = xyz[j * 3 + 0] - xyz[i * 3 + 0];
        float r1 = xyz[j * 3 + 1] - xyz[i * 3 + 1];
        float r2 = xyz[j * 3 + 2] - xyz[i * 3 + 2];
        float d = sqrtf(r0 * r0 + r1 * r1 + r2 * r2);
        float inv_d = 1.0f / d;
        float x = d * 0.2f;
        float env = 0.f;
        if (x < 1.f) {
            float x3 = x * x * x;
            env = 1.f - 10.f * x3 + 15.f * x3 * x - 6.f * x3 * x * x;
        }
        s_geo[t * 4 + 0] = r1 * inv_d;
        s_geo[t * 4 + 1] = r2 * inv_d;
        s_geo[t * 4 + 2] = r0 * inv_d;
        s_geo[t * 4 + 3] = msk;
        s_xs[t * 2 + 0] = x;
        s_xs[t * 2 + 1] = env * inv_d;
        s_ji[t] = j;
    }
    __syncthreads();

    #pragma unroll
    for (int rep = 0; rep < 4; ++rep) {              // 1024 sins
        int idx = t + rep * 256;
        int e = idx >> 4, k = idx & 15;
        s_rbf[e * 40 + k] = f2bf(sinf(s_xs[e * 2] * (float)k) * s_xs[e * 2 + 1]);
    }
    __syncthreads();

    // P2: h = ssp(rbf @ w1), M=64 rows (edges), wave owns 16 hidden cols
    {
        f32x4 z = {0.f, 0.f, 0.f, 0.f};
        #pragma unroll
        for (int mt = 0; mt < 4; ++mt) {
            short8 a = *(const short8*)&s_rbf[(16 * mt + nn) * 40 + q * 8];
            f32x4 h = __builtin_amdgcn_mfma_f32_16x16x32_bf16(a, b1, z, 0, 0, 0);
            #pragma unroll
            for (int r = 0; r < 4; ++r)
                s_h[(16 * mt + 4 * q + r) * 72 + 16 * wave + nn] = f2bf(ssp(h[r]));
        }
    }
    __syncthreads();

    // P3: fr = h @ w2
    {
        #pragma unroll
        for (int mt = 0; mt < 4; ++mt) {
            f32x4 acc = {0.f, 0.f, 0.f, 0.f};
            short8 a0 = *(const short8*)&s_h[(16 * mt + nn) * 72 + q * 8];
            acc = __builtin_amdgcn_mfma_f32_16x16x32_bf16(a0, b2_0, acc, 0, 0, 0);
            short8 a1 = *(const short8*)&s_h[(16 * mt + nn) * 72 + 32 + q * 8];
            acc = __builtin_amdgcn_mfma_f32_16x16x32_bf16(a1, b2_1, acc, 0, 0, 0);
            #pragma unroll
            for (int r = 0; r < 4; ++r)
                s_f[(16 * mt + 4 * q + r) * 68 + 16 * wave + nn] = acc[r];
        }
    }
    __syncthreads();

    // P4: coupling. wave -> 16 edges of node (wave>>1); lane == channel.
    {
        int node = wave >> 1;
        int ebase = wave * 16;
        float acc0a = 0.f, acc0b = 0.f;
        float P01[3] = {0.f, 0.f, 0.f};
        float P10[3] = {0.f, 0.f, 0.f};
        float P11[3] = {0.f, 0.f, 0.f};

        for (int bb = 0; bb < 16; bb += 4) {
            float4 pv[4];
            #pragma unroll
            for (int u = 0; u < 4; ++u)
                pv[u] = ((const float4*)pre_t)[(size_t)s_ji[ebase + bb + u] * 64 + lane];
            #pragma unroll
            for (int u = 0; u < 4; ++u) {
                int e = ebase + bb + u;
                float4 g = *(const float4*)&s_geo[e * 4];
                float ry = g.x, rz = g.y, rx = g.z;
                float f = s_f[e * 68 + lane] * g.w;
                float a0 = pv[u].x, a1y = pv[u].y, a1z = pv[u].z, a1x = pv[u].w;

                float a0f = a0 * f;
                acc0a += a0f;
                acc0b = fmaf(f, a1y * ry + a1z * rz + a1x * rx, acc0b);
                P01[0] = fmaf(a0f, ry, P01[0]);
                P01[1] = fmaf(a0f, rz, P01[1]);
                P01[2] = fmaf(a0f, rx, P01[2]);
                P10[0] = fmaf(a1y, f, P10[0]);
                P10[1] = fmaf(a1z, f, P10[1]);
                P10[2] = fmaf(a1x, f, P10[2]);
                P11[0] = fmaf(a1z * rx - a1x * rz, f, P11[0]);  // cy
                P11[1] = fmaf(a1x * ry - a1y * rx, f, P11[1]);  // cz
                P11[2] = fmaf(a1y * rz - a1z * ry, f, P11[2]);  // cx
            }
        }

        float* agg = &s_agg[node * 704];
        atomicAdd(&agg[lane], acc0a);
        atomicAdd(&agg[64 + lane], acc0b);
        #pragma unroll
        for (int m = 0; m < 3; ++m) {
            atomicAdd(&agg[128 + m * 192 + lane], P01[m]);
            atomicAdd(&agg[128 + m * 192 + 64 + lane], P10[m]);
            atomicAdd(&agg[128 + m * 192 + 128 + lane], P11[m]);
        }
    }
    __syncthreads();

    // store agg (2*704 floats = 352 float4)
    {
        const float4* s4 = (const float4*)s_agg;
        float4* g4 = (float4*)agg_g + (size_t)bi * 352;
        g4[t] = s4[t];
        if (t < 96) g4[256 + t] = s4[256 + t];
    }
}

// K3: batched finish. 8 nodes/block: ielin_a -> gate -> ielin_b -> residual.
// Weight columns streamed once per 8 nodes; agg rows broadcast from LDS.
__global__ __launch_bounds__(256) void finish_kernel(
    const float* __restrict__ agg_g, const float* __restrict__ feat,
    const float* __restrict__ w_a0, const float* __restrict__ w_a1,
    const float* __restrict__ w_b0, const float* __restrict__ w_b1,
    float* __restrict__ out)
{
    int bi = blockIdx.x;          // 512 blocks x 8 nodes
    int base = bi * 8;
    int t = threadIdx.x;
    int p = t >> 6, d = t & 63;

    __shared__ __align__(16) float s_agg[8 * 704];
    __shared__ __align__(16) float s_cout[8 * 256];
    __shared__ __align__(16) float s_gated[8 * 256];

    {
        const float4* src = (const float4*)agg_g + (size_t)bi * 1408;
        float4* dst = (float4*)s_agg;
        #pragma unroll
        for (int r = 0; r < 5; ++r) dst[t + r * 256] = src[t + r * 256];
        if (t < 128) dst[t + 1280] = src[t + 1280];
    }
    __syncthreads();

    // cout = ielin(agg, w_a0, w_a1)
    {
        float acc[8] = {0.f, 0.f, 0.f, 0.f, 0.f, 0.f, 0.f, 0.f};
        const float* w = (p == 0) ? w_a0 : w_a1;
        int K4 = (p == 0) ? 32 : 48;
        int aoff = (p == 0) ? 0 : 128 + (p - 1) * 192;
        for (int c4 = 0; c4 < K4; ++c4) {
            int c = c4 * 4;
            float wx = w[(c + 0) * 64 + d];
            float wy = w[(c + 1) * 64 + d];
            float wz = w[(c + 2) * 64 + d];
            float ww = w[(c + 3) * 64 + d];
            #pragma unroll
            for (int n = 0; n < 8; ++n) {
                float4 a = *(const float4*)&s_agg[n * 704 + aoff + c];
                acc[n] = fmaf(a.x, wx, fmaf(a.y, wy, fmaf(a.z, wz, fmaf(a.w, ww, acc[n]))));
            }
        }
        #pragma unroll
        for (int n = 0; n < 8; ++n) s_cout[n * 256 + t] = acc[n];
    }
    __syncthreads();

    // gate
    #pragma unroll
    for (int n = 0; n < 8; ++n) {
        float v = s_cout[n * 256 + t];
        float g;
        if (p == 0) {
            g = ssp(v);
        } else {
            float c0 = s_cout[n * 256 + 64 + d];
            float c1 = s_cout[n * 256 + 128 + d];
            float c2 = s_cout[n * 256 + 192 + d];
            g = ssp(sqrtf(fmaf(c0, c0, fmaf(c1, c1, fmaf(c2, c2, 1e-12f)))));
        }
        s_gated[n * 256 + t] = v * g;
    }
    __syncthreads();

    // out = feat + ielin(gated, w_b0, w_b1)
    {
        float acc[8] = {0.f, 0.f, 0.f, 0.f, 0.f, 0.f, 0.f, 0.f};
        const float* w = (p == 0) ? w_b0 : w_b1;
        int aoff = (p == 0) ? 0 : 64 + (p - 1) * 64;
        for (int c4 = 0; c4 < 16; ++c4) {
            int c = c4 * 4;
            float wx = w[(c + 0) * 64 + d];
            float wy = w[(c + 1) * 64 + d];
            float wz = w[(c + 2) * 64 + d];
            float ww = w[(c + 3) * 64 + d];
            #pragma unroll
            for (int n = 0; n < 8; ++n) {
                float4 a = *(const float4*)&s_gated[n * 256 + aoff + c];
                acc[n] = fmaf(a.x, wx, fmaf(a.y, wy, fmaf(a.z, wz, fmaf(a.w, ww, acc[n]))));
            }
        }
        #pragma unroll
        for (int n = 0; n < 8; ++n)
            out[(size_t)(base + n) * 256 + t] = feat[(size_t)(base + n) * 256 + t] + acc[n];
    }
}

extern "C" void kernel_launch(void* const* d_in, const int* in_sizes, int n_in,
                              void* d_out, int out_size, void* d_ws, size_t ws_size,
                              hipStream_t stream) {
    const float* xyz     = (const float*)d_in[0];
    const float* feat    = (const float*)d_in[1];
    const float* w_f1    = (const float*)d_in[2];
    const float* w_f2    = (const float*)d_in[3];
    const float* w_pre0  = (const float*)d_in[4];
    const float* w_pre1  = (const float*)d_in[5];
    const float* w_a0    = (const float*)d_in[6];
    const float* w_a1    = (const float*)d_in[7];
    const float* w_b0    = (const float*)d_in[8];
    const float* w_b1    = (const float*)d_in[9];
    const int* src_idx   = (const int*)d_in[10];
    const int* edge_mask = (const int*)d_in[11];
    float* out = (float*)d_out;

    float* pre_t = (float*)d_ws;                                  // 4 MB
    short* w1t_g = (short*)((char*)d_ws + (size_t)4194304);       // 4 KB
    short* w2t_g = w1t_g + 64 * 32;                               // 8 KB
    float* agg_g = (float*)((char*)d_ws + (size_t)4194304 + 16384); // 11.5 MB

    setup_kernel<<<8, 256, 0, stream>>>(w_f1, w_f2, w1t_g, w2t_g);
    pre_kernel<<<NN / 8, 256, 0, stream>>>(feat, w_pre0, w_pre1, pre_t);
    edge_kernel<<<NN / 2, 256, 0, stream>>>(xyz, pre_t, w1t_g, w2t_g,
                                            src_idx, edge_mask, agg_g);
    finish_kernel<<<NN / 8, 256, 0, stream>>>(agg_g, feat, w_a0, w_a1,
                                              w_b0, w_b1, out);
}

// Round 4
// 163.549 us; speedup vs baseline: 1.8540x; 1.0695x over previous
//
#include <hip/hip_runtime.h>
#include <math.h>

#define NN 4096
#define MM 32
#define LOG2F_ 0.69314718055994530942f

typedef __attribute__((ext_vector_type(8))) short short8;
typedef __attribute__((ext_vector_type(4))) float f32x4;

// shifted softplus via fast hw transcendentals; downstream is bf16-rounded
// so the ~1e-6 rel error of __expf/__logf is invisible.
__device__ __forceinline__ float ssp_fast(float x) {
    float sp = (x > 20.0f) ? x : __logf(1.0f + __expf(x));
    return sp - LOG2F_;
}

// float -> bf16 bits, round-to-nearest-even
__device__ __forceinline__ short f2bf(float x) {
    unsigned u = __float_as_uint(x);
    unsigned r = (u + 0x7FFFu + ((u >> 16) & 1u)) >> 16;
    return (short)r;
}
__device__ __forceinline__ float bf2f(short s) {
    return __uint_as_float(((unsigned)(unsigned short)s) << 16);
}

// Setup: w1t[n][k] (64x32 bf16, k>=16 zero) and w2t[n][k] (64x64 bf16).
__global__ __launch_bounds__(256) void setup_kernel(
    const float* __restrict__ w_f1, const float* __restrict__ w_f2,
    short* __restrict__ w1t, short* __restrict__ w2t)
{
    int t0 = blockIdx.x * 256 + threadIdx.x;
    int stride = gridDim.x * 256;
    for (int idx = t0; idx < 64 * 32; idx += stride) {
        int n = idx >> 5, k = idx & 31;
        w1t[idx] = (k < 16) ? f2bf(w_f1[k * 64 + n]) : (short)0;
    }
    for (int idx = t0; idx < 64 * 64; idx += stride) {
        int n = idx >> 6, k = idx & 63;
        w2t[idx] = f2bf(w_f2[k * 64 + n]);
    }
}

// K1: pre_t[node][ch*4 + p], p = {l0, y, z, x}. Weights staged in LDS once
// per block (coalesced float4), per-thread column read from LDS broadcasts.
__global__ __launch_bounds__(256) void pre_kernel(
    const float* __restrict__ feat, const float* __restrict__ w0,
    const float* __restrict__ w1, float* __restrict__ pre_t)
{
    int t = threadIdx.x;
    int base = blockIdx.x * 8;
    int ch = t >> 2, p = t & 3;

    __shared__ __align__(16) float s_w[2 * 4096];     // w0 | w1
    __shared__ __align__(16) float s_feat[8][256];

    {
        const float4* s0 = (const float4*)w0;
        const float4* s1 = (const float4*)w1;
        float4* d = (float4*)s_w;
        #pragma unroll
        for (int r = 0; r < 4; ++r) d[t + r * 256] = s0[t + r * 256];
        #pragma unroll
        for (int r = 0; r < 4; ++r) d[1024 + t + r * 256] = s1[t + r * 256];
        const float4* fs = (const float4*)(feat + (size_t)base * 256);
        float4* fd = (float4*)&s_feat[0][0];
        fd[t] = fs[t];
        fd[t + 256] = fs[t + 256];
    }
    __syncthreads();

    float wcol[64];
    const float* wsrc = (p == 0) ? s_w : s_w + 4096;
    #pragma unroll
    for (int c = 0; c < 64; ++c) wcol[c] = wsrc[c * 64 + ch];

    int aoff = (p == 0) ? 0 : 64 + (p - 1) * 64;
    #pragma unroll 2
    for (int n = 0; n < 8; ++n) {
        const float4* f4 = (const float4*)&s_feat[n][aoff];
        float acc = 0.f;
        #pragma unroll
        for (int c4 = 0; c4 < 16; ++c4) {
            float4 v = f4[c4];
            acc = fmaf(v.x, wcol[c4 * 4 + 0], acc);
            acc = fmaf(v.y, wcol[c4 * 4 + 1], acc);
            acc = fmaf(v.z, wcol[c4 * 4 + 2], acc);
            acc = fmaf(v.w, wcol[c4 * 4 + 3], acc);
        }
        pre_t[(size_t)(base + n) * 256 + t] = acc;
    }
}

// K2: 2 nodes/block. rbf -> MFMA radial MLP -> coupling (float4 gather) ->
// per-node agg (704 floats) to workspace. s_f stored bf16 for occupancy.
__global__ __launch_bounds__(256, 5) void edge_kernel(
    const float* __restrict__ xyz, const float* __restrict__ pre_t,
    const short* __restrict__ w1t_g, const short* __restrict__ w2t_g,
    const int* __restrict__ src_idx, const int* __restrict__ edge_mask,
    float* __restrict__ agg_g)
{
    int bi = blockIdx.x;           // 2048 blocks x 2 nodes
    int i0 = bi * 2;
    int t = threadIdx.x;
    int lane = t & 63;
    int wave = t >> 6;
    int q = lane >> 4;
    int nn = lane & 15;

    __shared__ __align__(16) short s_rbf[64 * 40];  // A tiles, K pad to 32
    __shared__ __align__(16) short s_h[64 * 72];
    __shared__ __align__(16) short s_f[64 * 72];    // filters bf16
    __shared__ __align__(16) float s_geo[64 * 4];   // {ry, rz, rx, mask}
    __shared__ float s_xs[64 * 2];                  // {x, env/d}
    __shared__ int   s_ji[64];
    __shared__ __align__(16) float s_agg[2 * 704];

    short8 b1   = *(const short8*)&w1t_g[(16 * wave + nn) * 32 + q * 8];
    short8 b2_0 = *(const short8*)&w2t_g[(16 * wave + nn) * 64 + q * 8];
    short8 b2_1 = *(const short8*)&w2t_g[(16 * wave + nn) * 64 + 32 + q * 8];

    for (int k = t; k < 1408; k += 256) s_agg[k] = 0.f;
    for (int idx = t; idx < 1024; idx += 256) {      // zero K-pad cols 16..31
        int e = idx >> 4, k = 16 + (idx & 15);
        s_rbf[e * 40 + k] = 0;
    }

    if (t < 64) {
        int node = t >> 5, e = t & 31;
        int i = i0 + node;
        int j = src_idx[i * MM + e];
        float msk = (float)edge_mask[i * MM + e];
        float r0 = xyz[j * 3 + 0] - xyz[i * 3 + 0];
        float r1 = xyz[j * 3 + 1] - xyz[i * 3 + 1];
        float r2 = xyz[j * 3 + 2] - xyz[i * 3 + 2];
        float d = sqrtf(r0 * r0 + r1 * r1 + r2 * r2);
        float inv_d = 1.0f / d;
        float x = d * 0.2f;
        float env = 0.f;
        if (x < 1.f) {
            float x3 = x * x * x;
            env = 1.f - 10.f * x3 + 15.f * x3 * x - 6.f * x3 * x * x;
        }
        s_geo[t * 4 + 0] = r1 * inv_d;
        s_geo[t * 4 + 1] = r2 * inv_d;
        s_geo[t * 4 + 2] = r0 * inv_d;
        s_geo[t * 4 + 3] = msk;
        s_xs[t * 2 + 0] = x;
        s_xs[t * 2 + 1] = env * inv_d;
        s_ji[t] = j;
    }
    __syncthreads();

    #pragma unroll
    for (int rep = 0; rep < 4; ++rep) {              // 1024 sins
        int idx = t + rep * 256;
        int e = idx >> 4, k = idx & 15;
        s_rbf[e * 40 + k] = f2bf(__sinf(s_xs[e * 2] * (float)k) * s_xs[e * 2 + 1]);
    }
    __syncthreads();

    // P2: h = ssp(rbf @ w1)
    {
        f32x4 z = {0.f, 0.f, 0.f, 0.f};
        #pragma unroll
        for (int mt = 0; mt < 4; ++mt) {
            short8 a = *(const short8*)&s_rbf[(16 * mt + nn) * 40 + q * 8];
            f32x4 h = __builtin_amdgcn_mfma_f32_16x16x32_bf16(a, b1, z, 0, 0, 0);
            #pragma unroll
            for (int r = 0; r < 4; ++r)
                s_h[(16 * mt + 4 * q + r) * 72 + 16 * wave + nn] = f2bf(ssp_fast(h[r]));
        }
    }
    __syncthreads();

    // P3: fr = h @ w2
    {
        #pragma unroll
        for (int mt = 0; mt < 4; ++mt) {
            f32x4 acc = {0.f, 0.f, 0.f, 0.f};
            short8 a0 = *(const short8*)&s_h[(16 * mt + nn) * 72 + q * 8];
            acc = __builtin_amdgcn_mfma_f32_16x16x32_bf16(a0, b2_0, acc, 0, 0, 0);
            short8 a1 = *(const short8*)&s_h[(16 * mt + nn) * 72 + 32 + q * 8];
            acc = __builtin_amdgcn_mfma_f32_16x16x32_bf16(a1, b2_1, acc, 0, 0, 0);
            #pragma unroll
            for (int r = 0; r < 4; ++r)
                s_f[(16 * mt + 4 * q + r) * 72 + 16 * wave + nn] = f2bf(acc[r]);
        }
    }
    __syncthreads();

    // P4: coupling. wave -> 16 edges of node (wave>>1); lane == channel.
    {
        int node = wave >> 1;
        int ebase = wave * 16;
        float acc0a = 0.f, acc0b = 0.f;
        float P01[3] = {0.f, 0.f, 0.f};
        float P10[3] = {0.f, 0.f, 0.f};
        float P11[3] = {0.f, 0.f, 0.f};

        for (int bb = 0; bb < 16; bb += 4) {
            float4 pv[4];
            #pragma unroll
            for (int u = 0; u < 4; ++u)
                pv[u] = ((const float4*)pre_t)[(size_t)s_ji[ebase + bb + u] * 64 + lane];
            #pragma unroll
            for (int u = 0; u < 4; ++u) {
                int e = ebase + bb + u;
                float4 g = *(const float4*)&s_geo[e * 4];
                float ry = g.x, rz = g.y, rx = g.z;
                float f = bf2f(s_f[e * 72 + lane]) * g.w;
                float a0 = pv[u].x, a1y = pv[u].y, a1z = pv[u].z, a1x = pv[u].w;

                float a0f = a0 * f;
                acc0a += a0f;
                acc0b = fmaf(f, a1y * ry + a1z * rz + a1x * rx, acc0b);
                P01[0] = fmaf(a0f, ry, P01[0]);
                P01[1] = fmaf(a0f, rz, P01[1]);
                P01[2] = fmaf(a0f, rx, P01[2]);
                P10[0] = fmaf(a1y, f, P10[0]);
                P10[1] = fmaf(a1z, f, P10[1]);
                P10[2] = fmaf(a1x, f, P10[2]);
                P11[0] = fmaf(a1z * rx - a1x * rz, f, P11[0]);  // cy
                P11[1] = fmaf(a1x * ry - a1y * rx, f, P11[1]);  // cz
                P11[2] = fmaf(a1y * rz - a1z * ry, f, P11[2]);  // cx
            }
        }

        float* agg = &s_agg[node * 704];
        atomicAdd(&agg[lane], acc0a);
        atomicAdd(&agg[64 + lane], acc0b);
        #pragma unroll
        for (int m = 0; m < 3; ++m) {
            atomicAdd(&agg[128 + m * 192 + lane], P01[m]);
            atomicAdd(&agg[128 + m * 192 + 64 + lane], P10[m]);
            atomicAdd(&agg[128 + m * 192 + 128 + lane], P11[m]);
        }
    }
    __syncthreads();

    {
        const float4* s4 = (const float4*)s_agg;
        float4* g4 = (float4*)agg_g + (size_t)bi * 352;
        g4[t] = s4[t];
        if (t < 96) g4[256 + t] = s4[256 + t];
    }
}

// K3: batched finish, 16 nodes/block: ielin_a -> gate -> ielin_b -> residual.
__global__ __launch_bounds__(256) void finish_kernel(
    const float* __restrict__ agg_g, const float* __restrict__ feat,
    const float* __restrict__ w_a0, const float* __restrict__ w_a1,
    const float* __restrict__ w_b0, const float* __restrict__ w_b1,
    float* __restrict__ out)
{
    int bi = blockIdx.x;          // 256 blocks x 16 nodes
    int base = bi * 16;
    int t = threadIdx.x;
    int p = t >> 6, d = t & 63;

    __shared__ __align__(16) float s_agg[16 * 704];
    __shared__ __align__(16) float s_cout[16 * 256];
    __shared__ __align__(16) float s_gated[16 * 256];

    {
        const float4* src = (const float4*)agg_g + (size_t)bi * 2816;
        float4* dst = (float4*)s_agg;
        #pragma unroll
        for (int r = 0; r < 11; ++r) dst[t + r * 256] = src[t + r * 256];
    }
    __syncthreads();

    // cout = ielin(agg, w_a0, w_a1)
    {
        float acc[16];
        #pragma unroll
        for (int n = 0; n < 16; ++n) acc[n] = 0.f;
        const float* w = (p == 0) ? w_a0 : w_a1;
        int K4 = (p == 0) ? 32 : 48;
        int aoff = (p == 0) ? 0 : 128 + (p - 1) * 192;
        for (int c4 = 0; c4 < K4; ++c4) {
            int c = c4 * 4;
            float wx = w[(c + 0) * 64 + d];
            float wy = w[(c + 1) * 64 + d];
            float wz = w[(c + 2) * 64 + d];
            float ww = w[(c + 3) * 64 + d];
            #pragma unroll
            for (int n = 0; n < 16; ++n) {
                float4 a = *(const float4*)&s_agg[n * 704 + aoff + c];
                acc[n] = fmaf(a.x, wx, fmaf(a.y, wy, fmaf(a.z, wz, fmaf(a.w, ww, acc[n]))));
            }
        }
        #pragma unroll
        for (int n = 0; n < 16; ++n) s_cout[n * 256 + t] = acc[n];
    }
    __syncthreads();

    // gate
    #pragma unroll 4
    for (int n = 0; n < 16; ++n) {
        float v = s_cout[n * 256 + t];
        float g;
        if (p == 0) {
            g = ssp_fast(v);
        } else {
            float c0 = s_cout[n * 256 + 64 + d];
            float c1 = s_cout[n * 256 + 128 + d];
            float c2 = s_cout[n * 256 + 192 + d];
            g = ssp_fast(sqrtf(fmaf(c0, c0, fmaf(c1, c1, fmaf(c2, c2, 1e-12f)))));
        }
        s_gated[n * 256 + t] = v * g;
    }
    __syncthreads();

    // out = feat + ielin(gated, w_b0, w_b1)
    {
        float acc[16];
        #pragma unroll
        for (int n = 0; n < 16; ++n) acc[n] = 0.f;
        const float* w = (p == 0) ? w_b0 : w_b1;
        int aoff = (p == 0) ? 0 : 64 + (p - 1) * 64;
        for (int c4 = 0; c4 < 16; ++c4) {
            int c = c4 * 4;
            float wx = w[(c + 0) * 64 + d];
            float wy = w[(c + 1) * 64 + d];
            float wz = w[(c + 2) * 64 + d];
            float ww = w[(c + 3) * 64 + d];
            #pragma unroll
            for (int n = 0; n < 16; ++n) {
                float4 a = *(const float4*)&s_gated[n * 256 + aoff + c];
                acc[n] = fmaf(a.x, wx, fmaf(a.y, wy, fmaf(a.z, wz, fmaf(a.w, ww, acc[n]))));
            }
        }
        #pragma unroll
        for (int n = 0; n < 16; ++n)
            out[(size_t)(base + n) * 256 + t] = feat[(size_t)(base + n) * 256 + t] + acc[n];
    }
}

extern "C" void kernel_launch(void* const* d_in, const int* in_sizes, int n_in,
                              void* d_out, int out_size, void* d_ws, size_t ws_size,
                              hipStream_t stream) {
    const float* xyz     = (const float*)d_in[0];
    const float* feat    = (const float*)d_in[1];
    const float* w_f1    = (const float*)d_in[2];
    const float* w_f2    = (const float*)d_in[3];
    const float* w_pre0  = (const float*)d_in[4];
    const float* w_pre1  = (const float*)d_in[5];
    const float* w_a0    = (const float*)d_in[6];
    const float* w_a1    = (const float*)d_in[7];
    const float* w_b0    = (const float*)d_in[8];
    const float* w_b1    = (const float*)d_in[9];
    const int* src_idx   = (const int*)d_in[10];
    const int* edge_mask = (const int*)d_in[11];
    float* out = (float*)d_out;

    float* pre_t = (float*)d_ws;                                    // 4 MB
    short* w1t_g = (short*)((char*)d_ws + (size_t)4194304);         // 4 KB
    short* w2t_g = w1t_g + 64 * 32;                                 // 8 KB
    float* agg_g = (float*)((char*)d_ws + (size_t)4194304 + 16384); // 11.5 MB

    setup_kernel<<<8, 256, 0, stream>>>(w_f1, w_f2, w1t_g, w2t_g);
    pre_kernel<<<NN / 8, 256, 0, stream>>>(feat, w_pre0, w_pre1, pre_t);
    edge_kernel<<<NN / 2, 256, 0, stream>>>(xyz, pre_t, w1t_g, w2t_g,
                                            src_idx, edge_mask, agg_g);
    finish_kernel<<<NN / 16, 256, 0, stream>>>(agg_g, feat, w_a0, w_a1,
                                               w_b0, w_b1, out);
}

// Round 5
// 147.141 us; speedup vs baseline: 2.0608x; 1.1115x over previous
//
#include <hip/hip_runtime.h>
#include <math.h>

#define NN 4096
#define MM 32
#define LOG2F_ 0.69314718055994530942f

typedef __attribute__((ext_vector_type(8))) short short8;
typedef __attribute__((ext_vector_type(4))) float f32x4;

// shifted softplus via fast hw transcendentals; downstream is bf16-rounded
// so the ~1e-6 rel error of __expf/__logf is invisible.
__device__ __forceinline__ float ssp_fast(float x) {
    float sp = (x > 20.0f) ? x : __logf(1.0f + __expf(x));
    return sp - LOG2F_;
}

// float -> bf16 bits, round-to-nearest-even
__device__ __forceinline__ short f2bf(float x) {
    unsigned u = __float_as_uint(x);
    unsigned r = (u + 0x7FFFu + ((u >> 16) & 1u)) >> 16;
    return (short)r;
}
__device__ __forceinline__ float bf2f(short s) {
    return __uint_as_float(((unsigned)(unsigned short)s) << 16);
}

// K1: pre_t[node][ch*4 + p], p = {l0, y, z, x}  (float4 per (node,channel)).
// Block 0 additionally converts w_f1/w_f2 to bf16 B^T layout (fused setup).
__global__ __launch_bounds__(256) void pre_kernel(
    const float* __restrict__ feat, const float* __restrict__ w0,
    const float* __restrict__ w1, float* __restrict__ pre_t,
    const float* __restrict__ w_f1, const float* __restrict__ w_f2,
    short* __restrict__ w1t, short* __restrict__ w2t)
{
    int t = threadIdx.x;
    int base = blockIdx.x * 8;
    int ch = t >> 2, p = t & 3;

    if (blockIdx.x == 0) {
        for (int idx = t; idx < 64 * 32; idx += 256) {
            int n = idx >> 5, k = idx & 31;
            w1t[idx] = (k < 16) ? f2bf(w_f1[k * 64 + n]) : (short)0;
        }
        for (int idx = t; idx < 64 * 64; idx += 256) {
            int n = idx >> 6, k = idx & 63;
            w2t[idx] = f2bf(w_f2[k * 64 + n]);
        }
    }

    __shared__ __align__(16) float s_w[2 * 4096];     // w0 | w1
    __shared__ __align__(16) float s_feat[8][256];

    {
        const float4* s0 = (const float4*)w0;
        const float4* s1 = (const float4*)w1;
        float4* d = (float4*)s_w;
        #pragma unroll
        for (int r = 0; r < 4; ++r) d[t + r * 256] = s0[t + r * 256];
        #pragma unroll
        for (int r = 0; r < 4; ++r) d[1024 + t + r * 256] = s1[t + r * 256];
        const float4* fs = (const float4*)(feat + (size_t)base * 256);
        float4* fd = (float4*)&s_feat[0][0];
        fd[t] = fs[t];
        fd[t + 256] = fs[t + 256];
    }
    __syncthreads();

    float wcol[64];
    const float* wsrc = (p == 0) ? s_w : s_w + 4096;
    #pragma unroll
    for (int c = 0; c < 64; ++c) wcol[c] = wsrc[c * 64 + ch];

    int aoff = (p == 0) ? 0 : 64 + (p - 1) * 64;
    #pragma unroll 2
    for (int n = 0; n < 8; ++n) {
        const float4* f4 = (const float4*)&s_feat[n][aoff];
        float acc = 0.f;
        #pragma unroll
        for (int c4 = 0; c4 < 16; ++c4) {
            float4 v = f4[c4];
            acc = fmaf(v.x, wcol[c4 * 4 + 0], acc);
            acc = fmaf(v.y, wcol[c4 * 4 + 1], acc);
            acc = fmaf(v.z, wcol[c4 * 4 + 2], acc);
            acc = fmaf(v.w, wcol[c4 * 4 + 3], acc);
        }
        pre_t[(size_t)(base + n) * 256 + t] = acc;
    }
}

// K2: 2 nodes/block, fully fused: rbf -> MFMA radial MLP -> coupling
// (pipelined float4 gather) -> agg in LDS -> ielin_a -> gate -> ielin_b
// -> residual. No agg round-trip, no separate finish kernel.
__global__ __launch_bounds__(256, 4) void edge_kernel(
    const float* __restrict__ xyz, const float* __restrict__ feat,
    const float* __restrict__ pre_t,
    const short* __restrict__ w1t_g, const short* __restrict__ w2t_g,
    const float* __restrict__ w_a0, const float* __restrict__ w_a1,
    const float* __restrict__ w_b0, const float* __restrict__ w_b1,
    const int* __restrict__ src_idx, const int* __restrict__ edge_mask,
    float* __restrict__ out)
{
    int bi = blockIdx.x;           // 2048 blocks x 2 nodes
    int i0 = bi * 2;
    int t = threadIdx.x;
    int lane = t & 63;
    int wave = t >> 6;
    int q = lane >> 4;
    int nn = lane & 15;

    __shared__ __align__(16) short s_rbf[64 * 40];  // A tiles, K pad to 32
    __shared__ __align__(16) short s_h[64 * 72];    // hidden; later cout/gated
    __shared__ __align__(16) short s_f[64 * 72];    // filters bf16
    __shared__ __align__(16) float s_geo[64 * 4];   // {ry, rz, rx, mask}
    __shared__ float s_xs[64 * 2];                  // {x, env/d}
    __shared__ int   s_ji[64];
    __shared__ __align__(16) float s_agg[2 * 704];

    short8 b1   = *(const short8*)&w1t_g[(16 * wave + nn) * 32 + q * 8];
    short8 b2_0 = *(const short8*)&w2t_g[(16 * wave + nn) * 64 + q * 8];
    short8 b2_1 = *(const short8*)&w2t_g[(16 * wave + nn) * 64 + 32 + q * 8];

    for (int k = t; k < 1408; k += 256) s_agg[k] = 0.f;
    for (int idx = t; idx < 1024; idx += 256) {      // zero K-pad cols 16..31
        int e = idx >> 4, k = 16 + (idx & 15);
        s_rbf[e * 40 + k] = 0;
    }

    if (t < 64) {
        int node = t >> 5, e = t & 31;
        int i = i0 + node;
        int j = src_idx[i * MM + e];
        float msk = (float)edge_mask[i * MM + e];
        float r0 = xyz[j * 3 + 0] - xyz[i * 3 + 0];
        float r1 = xyz[j * 3 + 1] - xyz[i * 3 + 1];
        float r2 = xyz[j * 3 + 2] - xyz[i * 3 + 2];
        float d = sqrtf(r0 * r0 + r1 * r1 + r2 * r2);
        float inv_d = 1.0f / d;
        float x = d * 0.2f;
        float env = 0.f;
        if (x < 1.f) {
            float x3 = x * x * x;
            env = 1.f - 10.f * x3 + 15.f * x3 * x - 6.f * x3 * x * x;
        }
        s_geo[t * 4 + 0] = r1 * inv_d;
        s_geo[t * 4 + 1] = r2 * inv_d;
        s_geo[t * 4 + 2] = r0 * inv_d;
        s_geo[t * 4 + 3] = msk;
        s_xs[t * 2 + 0] = x;
        s_xs[t * 2 + 1] = env * inv_d;
        s_ji[t] = j;
    }
    __syncthreads();

    #pragma unroll
    for (int rep = 0; rep < 4; ++rep) {              // 1024 sins
        int idx = t + rep * 256;
        int e = idx >> 4, k = idx & 15;
        s_rbf[e * 40 + k] = f2bf(__sinf(s_xs[e * 2] * (float)k) * s_xs[e * 2 + 1]);
    }
    __syncthreads();

    // P2: h = ssp(rbf @ w1)
    {
        f32x4 z = {0.f, 0.f, 0.f, 0.f};
        #pragma unroll
        for (int mt = 0; mt < 4; ++mt) {
            short8 a = *(const short8*)&s_rbf[(16 * mt + nn) * 40 + q * 8];
            f32x4 h = __builtin_amdgcn_mfma_f32_16x16x32_bf16(a, b1, z, 0, 0, 0);
            #pragma unroll
            for (int r = 0; r < 4; ++r)
                s_h[(16 * mt + 4 * q + r) * 72 + 16 * wave + nn] = f2bf(ssp_fast(h[r]));
        }
    }
    __syncthreads();

    // P3: fr = h @ w2
    {
        #pragma unroll
        for (int mt = 0; mt < 4; ++mt) {
            f32x4 acc = {0.f, 0.f, 0.f, 0.f};
            short8 a0 = *(const short8*)&s_h[(16 * mt + nn) * 72 + q * 8];
            acc = __builtin_amdgcn_mfma_f32_16x16x32_bf16(a0, b2_0, acc, 0, 0, 0);
            short8 a1 = *(const short8*)&s_h[(16 * mt + nn) * 72 + 32 + q * 8];
            acc = __builtin_amdgcn_mfma_f32_16x16x32_bf16(a1, b2_1, acc, 0, 0, 0);
            #pragma unroll
            for (int r = 0; r < 4; ++r)
                s_f[(16 * mt + 4 * q + r) * 72 + 16 * wave + nn] = f2bf(acc[r]);
        }
    }
    __syncthreads();

    // P4: coupling. wave -> 16 edges of node (wave>>1); lane == channel.
    // Double-buffered gather: next 4 edges' float4 loads in flight while
    // the current 4 are processed.
    {
        int ebase = wave * 16;
        float acc0a = 0.f, acc0b = 0.f;
        float P01[3] = {0.f, 0.f, 0.f};
        float P10[3] = {0.f, 0.f, 0.f};
        float P11[3] = {0.f, 0.f, 0.f};
        float4 pv[2][4];

        #pragma unroll
        for (int u = 0; u < 4; ++u)
            pv[0][u] = ((const float4*)pre_t)[(size_t)s_ji[ebase + u] * 64 + lane];

        #pragma unroll
        for (int bb = 0; bb < 16; bb += 4) {
            int cur = (bb >> 2) & 1, nxt = cur ^ 1;
            if (bb < 12) {
                #pragma unroll
                for (int u = 0; u < 4; ++u)
                    pv[nxt][u] = ((const float4*)pre_t)[(size_t)s_ji[ebase + bb + 4 + u] * 64 + lane];
            }
            #pragma unroll
            for (int u = 0; u < 4; ++u) {
                int e = ebase + bb + u;
                float4 g = *(const float4*)&s_geo[e * 4];
                float ry = g.x, rz = g.y, rx = g.z;
                float f = bf2f(s_f[e * 72 + lane]) * g.w;
                float a0 = pv[cur][u].x, a1y = pv[cur][u].y;
                float a1z = pv[cur][u].z, a1x = pv[cur][u].w;

                float a0f = a0 * f;
                acc0a += a0f;
                acc0b = fmaf(f, a1y * ry + a1z * rz + a1x * rx, acc0b);
                P01[0] = fmaf(a0f, ry, P01[0]);
                P01[1] = fmaf(a0f, rz, P01[1]);
                P01[2] = fmaf(a0f, rx, P01[2]);
                P10[0] = fmaf(a1y, f, P10[0]);
                P10[1] = fmaf(a1z, f, P10[1]);
                P10[2] = fmaf(a1x, f, P10[2]);
                P11[0] = fmaf(a1z * rx - a1x * rz, f, P11[0]);  // cy
                P11[1] = fmaf(a1x * ry - a1y * rx, f, P11[1]);  // cz
                P11[2] = fmaf(a1y * rz - a1z * ry, f, P11[2]);  // cx
            }
        }

        float* agg = &s_agg[(wave >> 1) * 704];
        atomicAdd(&agg[lane], acc0a);
        atomicAdd(&agg[64 + lane], acc0b);
        #pragma unroll
        for (int m = 0; m < 3; ++m) {
            atomicAdd(&agg[128 + m * 192 + lane], P01[m]);
            atomicAdd(&agg[128 + m * 192 + 64 + lane], P10[m]);
            atomicAdd(&agg[128 + m * 192 + 128 + lane], P11[m]);
        }
    }
    __syncthreads();

    // ---- P5: fused finish for the 2 nodes. s_cout/s_gated alias dead s_h.
    float* s_cout  = (float*)s_h;          // 2 x 256 floats
    float* s_gated = ((float*)s_h) + 512;  // 2 x 256 floats

    // cout = ielin(agg, w_a0, w_a1); weight loads shared across both nodes
    {
        const float* w = (wave == 0) ? w_a0 : w_a1;
        int K4 = (wave == 0) ? 32 : 48;
        int aoff = (wave == 0) ? 0 : 128 + (wave - 1) * 192;
        float acc0 = 0.f, acc1 = 0.f;
        for (int c4 = 0; c4 < K4; ++c4) {
            int c = c4 * 4;
            float wx = w[(c + 0) * 64 + lane];
            float wy = w[(c + 1) * 64 + lane];
            float wz = w[(c + 2) * 64 + lane];
            float ww = w[(c + 3) * 64 + lane];
            float4 a0v = *(const float4*)&s_agg[aoff + c];
            float4 a1v = *(const float4*)&s_agg[704 + aoff + c];
            acc0 = fmaf(a0v.x, wx, fmaf(a0v.y, wy, fmaf(a0v.z, wz, fmaf(a0v.w, ww, acc0))));
            acc1 = fmaf(a1v.x, wx, fmaf(a1v.y, wy, fmaf(a1v.z, wz, fmaf(a1v.w, ww, acc1))));
        }
        s_cout[t] = acc0;
        s_cout[256 + t] = acc1;
    }
    __syncthreads();

    // gate
    #pragma unroll
    for (int n = 0; n < 2; ++n) {
        float v = s_cout[n * 256 + t];
        float g;
        if (wave == 0) {
            g = ssp_fast(v);
        } else {
            float c0 = s_cout[n * 256 + 64 + lane];
            float c1 = s_cout[n * 256 + 128 + lane];
            float c2 = s_cout[n * 256 + 192 + lane];
            g = ssp_fast(sqrtf(fmaf(c0, c0, fmaf(c1, c1, fmaf(c2, c2, 1e-12f)))));
        }
        s_gated[n * 256 + t] = v * g;
    }
    __syncthreads();

    // out = feat + ielin(gated, w_b0, w_b1)
    {
        const float* w = (wave == 0) ? w_b0 : w_b1;
        int aoff = (wave == 0) ? 0 : 64 + (wave - 1) * 64;
        float acc0 = 0.f, acc1 = 0.f;
        for (int c4 = 0; c4 < 16; ++c4) {
            int c = c4 * 4;
            float wx = w[(c + 0) * 64 + lane];
            float wy = w[(c + 1) * 64 + lane];
            float wz = w[(c + 2) * 64 + lane];
            float ww = w[(c + 3) * 64 + lane];
            float4 g0 = *(const float4*)&s_gated[aoff + c];
            float4 g1 = *(const float4*)&s_gated[256 + aoff + c];
            acc0 = fmaf(g0.x, wx, fmaf(g0.y, wy, fmaf(g0.z, wz, fmaf(g0.w, ww, acc0))));
            acc1 = fmaf(g1.x, wx, fmaf(g1.y, wy, fmaf(g1.z, wz, fmaf(g1.w, ww, acc1))));
        }
        out[(size_t)i0 * 256 + t]       = feat[(size_t)i0 * 256 + t] + acc0;
        out[(size_t)(i0 + 1) * 256 + t] = feat[(size_t)(i0 + 1) * 256 + t] + acc1;
    }
}

extern "C" void kernel_launch(void* const* d_in, const int* in_sizes, int n_in,
                              void* d_out, int out_size, void* d_ws, size_t ws_size,
                              hipStream_t stream) {
    const float* xyz     = (const float*)d_in[0];
    const float* feat    = (const float*)d_in[1];
    const float* w_f1    = (const float*)d_in[2];
    const float* w_f2    = (const float*)d_in[3];
    const float* w_pre0  = (const float*)d_in[4];
    const float* w_pre1  = (const float*)d_in[5];
    const float* w_a0    = (const float*)d_in[6];
    const float* w_a1    = (const float*)d_in[7];
    const float* w_b0    = (const float*)d_in[8];
    const float* w_b1    = (const float*)d_in[9];
    const int* src_idx   = (const int*)d_in[10];
    const int* edge_mask = (const int*)d_in[11];
    float* out = (float*)d_out;

    float* pre_t = (float*)d_ws;                              // 4 MB
    short* w1t_g = (short*)((char*)d_ws + (size_t)4194304);   // 4 KB
    short* w2t_g = w1t_g + 64 * 32;                           // 8 KB

    pre_kernel<<<NN / 8, 256, 0, stream>>>(feat, w_pre0, w_pre1, pre_t,
                                           w_f1, w_f2, w1t_g, w2t_g);
    edge_kernel<<<NN / 2, 256, 0, stream>>>(xyz, feat, pre_t, w1t_g, w2t_g,
                                            w_a0, w_a1, w_b0, w_b1,
                                            src_idx, edge_mask, out);
}

// Round 6
// 143.241 us; speedup vs baseline: 2.1169x; 1.0272x over previous
//
#include <hip/hip_runtime.h>
#include <math.h>

#define NN 4096
#define MM 32
#define LOG2F_ 0.69314718055994530942f

typedef __attribute__((ext_vector_type(8))) short short8;
typedef __attribute__((ext_vector_type(4))) float f32x4;

// shifted softplus via fast hw transcendentals; downstream is bf16-rounded
// so the ~1e-6 rel error of __expf/__logf is invisible.
__device__ __forceinline__ float ssp_fast(float x) {
    float sp = (x > 20.0f) ? x : __logf(1.0f + __expf(x));
    return sp - LOG2F_;
}

// float -> bf16 bits, round-to-nearest-even
__device__ __forceinline__ short f2bf(float x) {
    unsigned u = __float_as_uint(x);
    unsigned r = (u + 0x7FFFu + ((u >> 16) & 1u)) >> 16;
    return (short)r;
}
__device__ __forceinline__ float bf2f(short s) {
    return __uint_as_float(((unsigned)(unsigned short)s) << 16);
}

// K1: pre = ielin(feat, w_pre0, w_pre1) via MFMA. 8 nodes/block.
// pre_t[node][ch*4 + p], p = {l0, y, z, x} (float4 per (node,channel)).
// No private arrays -> no scratch spill (the old wcol[64] variant was the
// hidden ~60us cost). Block 0 also converts w_f1/w_f2 to bf16 B^T layout.
__global__ __launch_bounds__(256) void pre_kernel(
    const float* __restrict__ feat, const float* __restrict__ w0,
    const float* __restrict__ w1, float* __restrict__ pre_t,
    const float* __restrict__ w_f1, const float* __restrict__ w_f2,
    short* __restrict__ w1t, short* __restrict__ w2t)
{
    int t = threadIdx.x;
    int base = blockIdx.x * 8;
    int lane = t & 63, wave = t >> 6, q = lane >> 4, nn = lane & 15;

    if (blockIdx.x == 0) {
        for (int idx = t; idx < 64 * 32; idx += 256) {
            int n = idx >> 5, k = idx & 31;
            w1t[idx] = (k < 16) ? f2bf(w_f1[k * 64 + n]) : (short)0;
        }
        for (int idx = t; idx < 64 * 64; idx += 256) {
            int n = idx >> 6, k = idx & 63;
            w2t[idx] = f2bf(w_f2[k * 64 + n]);
        }
    }

    __shared__ __align__(16) short s_a0[16 * 72];      // l0 feat rows (8 valid)
    __shared__ __align__(16) short s_a1[2][16 * 72];   // l1 feat rows (24 valid)
    __shared__ __align__(16) short s_w0[64 * 72];      // w_pre0^T bf16
    __shared__ __align__(16) short s_w1[64 * 72];      // w_pre1^T bf16
    __shared__ __align__(16) float s_po[8][256];       // staged output

    // zero invalid A rows (a0 rows 8-15, a1[1] rows 8-15), k 0..63
    for (int idx = t; idx < 512; idx += 256) {
        int r = 8 + (idx >> 6), k = idx & 63;
        s_a0[r * 72 + k] = 0;
        s_a1[1][r * 72 + k] = 0;
    }
    // stage weights transposed -> bf16 (wave handles 16 k's, coalesced reads)
    #pragma unroll 4
    for (int kk = 0; kk < 16; ++kk) {
        int k = wave * 16 + kk;
        s_w0[lane * 72 + k] = f2bf(w0[k * 64 + lane]);
        s_w1[lane * 72 + k] = f2bf(w1[k * 64 + lane]);
    }
    // stage feat -> bf16 A tiles
    {
        const float4* f4 = (const float4*)(feat + (size_t)base * 256);
        #pragma unroll
        for (int rep = 0; rep < 2; ++rep) {
            int idx = t + rep * 256;
            float4 v = f4[idx];
            int node = idx >> 6, c = (idx & 63) * 4;
            short* dst;
            if (c < 64) {
                dst = &s_a0[node * 72 + c];
            } else {
                int mm = (c >> 6) - 1, ch = c & 63;
                int row = node * 3 + mm;
                dst = &s_a1[row >> 4][(row & 15) * 72 + ch];
            }
            dst[0] = f2bf(v.x); dst[1] = f2bf(v.y);
            dst[2] = f2bf(v.z); dst[3] = f2bf(v.w);
        }
    }
    __syncthreads();

    // B fragments: wave owns output cols 16*wave..16*wave+15
    short8 bw0[2], bw1[2];
    #pragma unroll
    for (int kc = 0; kc < 2; ++kc) {
        bw0[kc] = *(const short8*)&s_w0[(16 * wave + nn) * 72 + kc * 32 + q * 8];
        bw1[kc] = *(const short8*)&s_w1[(16 * wave + nn) * 72 + kc * 32 + q * 8];
    }

    // l0: C rows 0-7 = nodes
    {
        f32x4 acc = {0.f, 0.f, 0.f, 0.f};
        #pragma unroll
        for (int kc = 0; kc < 2; ++kc) {
            short8 a = *(const short8*)&s_a0[nn * 72 + kc * 32 + q * 8];
            acc = __builtin_amdgcn_mfma_f32_16x16x32_bf16(a, bw0[kc], acc, 0, 0, 0);
        }
        if (q < 2) {
            #pragma unroll
            for (int r = 0; r < 4; ++r) {
                int node = 4 * q + r;
                s_po[node][(16 * wave + nn) * 4 + 0] = acc[r];
            }
        }
    }
    // l1: rows = node*3 + mm, two 16-row tiles (24 valid rows)
    #pragma unroll
    for (int tile = 0; tile < 2; ++tile) {
        f32x4 acc = {0.f, 0.f, 0.f, 0.f};
        #pragma unroll
        for (int kc = 0; kc < 2; ++kc) {
            short8 a = *(const short8*)&s_a1[tile][nn * 72 + kc * 32 + q * 8];
            acc = __builtin_amdgcn_mfma_f32_16x16x32_bf16(a, bw1[kc], acc, 0, 0, 0);
        }
        #pragma unroll
        for (int r = 0; r < 4; ++r) {
            int row = tile * 16 + 4 * q + r;
            if (row < 24) {
                unsigned node = (unsigned)row / 3u;
                int mm = row - (int)node * 3;
                s_po[node][(16 * wave + nn) * 4 + 1 + mm] = acc[r];
            }
        }
    }
    __syncthreads();

    // coalesced float4 store
    #pragma unroll
    for (int rep = 0; rep < 2; ++rep) {
        int idx = t + rep * 256;
        int node = idx >> 6, c4 = idx & 63;
        *(float4*)&pre_t[(size_t)(base + node) * 256 + c4 * 4] =
            *(const float4*)&s_po[node][c4 * 4];
    }
}

// K2: 2 nodes/block, fully fused: rbf -> MFMA radial MLP -> coupling
// (pipelined float4 gather) -> agg in LDS -> ielin_a -> gate -> ielin_b
// -> residual.
__global__ __launch_bounds__(256, 4) void edge_kernel(
    const float* __restrict__ xyz, const float* __restrict__ feat,
    const float* __restrict__ pre_t,
    const short* __restrict__ w1t_g, const short* __restrict__ w2t_g,
    const float* __restrict__ w_a0, const float* __restrict__ w_a1,
    const float* __restrict__ w_b0, const float* __restrict__ w_b1,
    const int* __restrict__ src_idx, const int* __restrict__ edge_mask,
    float* __restrict__ out)
{
    int bi = blockIdx.x;           // 2048 blocks x 2 nodes
    int i0 = bi * 2;
    int t = threadIdx.x;
    int lane = t & 63;
    int wave = t >> 6;
    int q = lane >> 4;
    int nn = lane & 15;

    __shared__ __align__(16) short s_rbf[64 * 40];  // A tiles, K pad to 32
    __shared__ __align__(16) short s_h[64 * 72];    // hidden; later cout/gated
    __shared__ __align__(16) short s_f[64 * 72];    // filters bf16
    __shared__ __align__(16) float s_geo[64 * 4];   // {ry, rz, rx, mask}
    __shared__ float s_xs[64 * 2];                  // {x, env/d}
    __shared__ int   s_ji[64];
    __shared__ __align__(16) float s_agg[2 * 704];

    short8 b1   = *(const short8*)&w1t_g[(16 * wave + nn) * 32 + q * 8];
    short8 b2_0 = *(const short8*)&w2t_g[(16 * wave + nn) * 64 + q * 8];
    short8 b2_1 = *(const short8*)&w2t_g[(16 * wave + nn) * 64 + 32 + q * 8];

    for (int k = t; k < 1408; k += 256) s_agg[k] = 0.f;
    for (int idx = t; idx < 1024; idx += 256) {      // zero K-pad cols 16..31
        int e = idx >> 4, k = 16 + (idx & 15);
        s_rbf[e * 40 + k] = 0;
    }

    if (t < 64) {
        int node = t >> 5, e = t & 31;
        int i = i0 + node;
        int j = src_idx[i * MM + e];
        float msk = (float)edge_mask[i * MM + e];
        float r0 = xyz[j * 3 + 0] - xyz[i * 3 + 0];
        float r1 = xyz[j * 3 + 1] - xyz[i * 3 + 1];
        float r2 = xyz[j * 3 + 2] - xyz[i * 3 + 2];
        float d = sqrtf(r0 * r0 + r1 * r1 + r2 * r2);
        float inv_d = 1.0f / d;
        float x = d * 0.2f;
        float env = 0.f;
        if (x < 1.f) {
            float x3 = x * x * x;
            env = 1.f - 10.f * x3 + 15.f * x3 * x - 6.f * x3 * x * x;
        }
        s_geo[t * 4 + 0] = r1 * inv_d;
        s_geo[t * 4 + 1] = r2 * inv_d;
        s_geo[t * 4 + 2] = r0 * inv_d;
        s_geo[t * 4 + 3] = msk;
        s_xs[t * 2 + 0] = x;
        s_xs[t * 2 + 1] = env * inv_d;
        s_ji[t] = j;
    }
    __syncthreads();

    #pragma unroll
    for (int rep = 0; rep < 4; ++rep) {              // 1024 sins
        int idx = t + rep * 256;
        int e = idx >> 4, k = idx & 15;
        s_rbf[e * 40 + k] = f2bf(__sinf(s_xs[e * 2] * (float)k) * s_xs[e * 2 + 1]);
    }
    __syncthreads();

    // P2: h = ssp(rbf @ w1)
    {
        f32x4 z = {0.f, 0.f, 0.f, 0.f};
        #pragma unroll
        for (int mt = 0; mt < 4; ++mt) {
            short8 a = *(const short8*)&s_rbf[(16 * mt + nn) * 40 + q * 8];
            f32x4 h = __builtin_amdgcn_mfma_f32_16x16x32_bf16(a, b1, z, 0, 0, 0);
            #pragma unroll
            for (int r = 0; r < 4; ++r)
                s_h[(16 * mt + 4 * q + r) * 72 + 16 * wave + nn] = f2bf(ssp_fast(h[r]));
        }
    }
    __syncthreads();

    // P3: fr = h @ w2
    {
        #pragma unroll
        for (int mt = 0; mt < 4; ++mt) {
            f32x4 acc = {0.f, 0.f, 0.f, 0.f};
            short8 a0 = *(const short8*)&s_h[(16 * mt + nn) * 72 + q * 8];
            acc = __builtin_amdgcn_mfma_f32_16x16x32_bf16(a0, b2_0, acc, 0, 0, 0);
            short8 a1 = *(const short8*)&s_h[(16 * mt + nn) * 72 + 32 + q * 8];
            acc = __builtin_amdgcn_mfma_f32_16x16x32_bf16(a1, b2_1, acc, 0, 0, 0);
            #pragma unroll
            for (int r = 0; r < 4; ++r)
                s_f[(16 * mt + 4 * q + r) * 72 + 16 * wave + nn] = f2bf(acc[r]);
        }
    }
    __syncthreads();

    // P4: coupling. wave -> 16 edges of node (wave>>1); lane == channel.
    {
        int ebase = wave * 16;
        float acc0a = 0.f, acc0b = 0.f;
        float P01[3] = {0.f, 0.f, 0.f};
        float P10[3] = {0.f, 0.f, 0.f};
        float P11[3] = {0.f, 0.f, 0.f};
        float4 pv[2][4];

        #pragma unroll
        for (int u = 0; u < 4; ++u)
            pv[0][u] = ((const float4*)pre_t)[(size_t)s_ji[ebase + u] * 64 + lane];

        #pragma unroll
        for (int bb = 0; bb < 16; bb += 4) {
            int cur = (bb >> 2) & 1, nxt = cur ^ 1;
            if (bb < 12) {
                #pragma unroll
                for (int u = 0; u < 4; ++u)
                    pv[nxt][u] = ((const float4*)pre_t)[(size_t)s_ji[ebase + bb + 4 + u] * 64 + lane];
            }
            #pragma unroll
            for (int u = 0; u < 4; ++u) {
                int e = ebase + bb + u;
                float4 g = *(const float4*)&s_geo[e * 4];
                float ry = g.x, rz = g.y, rx = g.z;
                float f = bf2f(s_f[e * 72 + lane]) * g.w;
                float a0 = pv[cur][u].x, a1y = pv[cur][u].y;
                float a1z = pv[cur][u].z, a1x = pv[cur][u].w;

                float a0f = a0 * f;
                acc0a += a0f;
                acc0b = fmaf(f, a1y * ry + a1z * rz + a1x * rx, acc0b);
                P01[0] = fmaf(a0f, ry, P01[0]);
                P01[1] = fmaf(a0f, rz, P01[1]);
                P01[2] = fmaf(a0f, rx, P01[2]);
                P10[0] = fmaf(a1y, f, P10[0]);
                P10[1] = fmaf(a1z, f, P10[1]);
                P10[2] = fmaf(a1x, f, P10[2]);
                P11[0] = fmaf(a1z * rx - a1x * rz, f, P11[0]);  // cy
                P11[1] = fmaf(a1x * ry - a1y * rx, f, P11[1]);  // cz
                P11[2] = fmaf(a1y * rz - a1z * ry, f, P11[2]);  // cx
            }
        }

        float* agg = &s_agg[(wave >> 1) * 704];
        atomicAdd(&agg[lane], acc0a);
        atomicAdd(&agg[64 + lane], acc0b);
        #pragma unroll
        for (int m = 0; m < 3; ++m) {
            atomicAdd(&agg[128 + m * 192 + lane], P01[m]);
            atomicAdd(&agg[128 + m * 192 + 64 + lane], P10[m]);
            atomicAdd(&agg[128 + m * 192 + 128 + lane], P11[m]);
        }
    }
    __syncthreads();

    // ---- P5: fused finish for the 2 nodes. s_cout/s_gated alias dead s_h.
    float* s_cout  = (float*)s_h;          // 2 x 256 floats
    float* s_gated = ((float*)s_h) + 512;  // 2 x 256 floats

    // cout = ielin(agg, w_a0, w_a1); weight loads shared across both nodes
    {
        const float* w = (wave == 0) ? w_a0 : w_a1;
        int K4 = (wave == 0) ? 32 : 48;
        int aoff = (wave == 0) ? 0 : 128 + (wave - 1) * 192;
        float acc0 = 0.f, acc1 = 0.f;
        for (int c4 = 0; c4 < K4; ++c4) {
            int c = c4 * 4;
            float wx = w[(c + 0) * 64 + lane];
            float wy = w[(c + 1) * 64 + lane];
            float wz = w[(c + 2) * 64 + lane];
            float ww = w[(c + 3) * 64 + lane];
            float4 a0v = *(const float4*)&s_agg[aoff + c];
            float4 a1v = *(const float4*)&s_agg[704 + aoff + c];
            acc0 = fmaf(a0v.x, wx, fmaf(a0v.y, wy, fmaf(a0v.z, wz, fmaf(a0v.w, ww, acc0))));
            acc1 = fmaf(a1v.x, wx, fmaf(a1v.y, wy, fmaf(a1v.z, wz, fmaf(a1v.w, ww, acc1))));
        }
        s_cout[t] = acc0;
        s_cout[256 + t] = acc1;
    }
    __syncthreads();

    // gate
    #pragma unroll
    for (int n = 0; n < 2; ++n) {
        float v = s_cout[n * 256 + t];
        float g;
        if (wave == 0) {
            g = ssp_fast(v);
        } else {
            float c0 = s_cout[n * 256 + 64 + lane];
            float c1 = s_cout[n * 256 + 128 + lane];
            float c2 = s_cout[n * 256 + 192 + lane];
            g = ssp_fast(sqrtf(fmaf(c0, c0, fmaf(c1, c1, fmaf(c2, c2, 1e-12f)))));
        }
        s_gated[n * 256 + t] = v * g;
    }
    __syncthreads();

    // out = feat + ielin(gated, w_b0, w_b1)
    {
        const float* w = (wave == 0) ? w_b0 : w_b1;
        int aoff = (wave == 0) ? 0 : 64 + (wave - 1) * 64;
        float acc0 = 0.f, acc1 = 0.f;
        for (int c4 = 0; c4 < 16; ++c4) {
            int c = c4 * 4;
            float wx = w[(c + 0) * 64 + lane];
            float wy = w[(c + 1) * 64 + lane];
            float wz = w[(c + 2) * 64 + lane];
            float ww = w[(c + 3) * 64 + lane];
            float4 g0 = *(const float4*)&s_gated[aoff + c];
            float4 g1 = *(const float4*)&s_gated[256 + aoff + c];
            acc0 = fmaf(g0.x, wx, fmaf(g0.y, wy, fmaf(g0.z, wz, fmaf(g0.w, ww, acc0))));
            acc1 = fmaf(g1.x, wx, fmaf(g1.y, wy, fmaf(g1.z, wz, fmaf(g1.w, ww, acc1))));
        }
        out[(size_t)i0 * 256 + t]       = feat[(size_t)i0 * 256 + t] + acc0;
        out[(size_t)(i0 + 1) * 256 + t] = feat[(size_t)(i0 + 1) * 256 + t] + acc1;
    }
}

extern "C" void kernel_launch(void* const* d_in, const int* in_sizes, int n_in,
                              void* d_out, int out_size, void* d_ws, size_t ws_size,
                              hipStream_t stream) {
    const float* xyz     = (const float*)d_in[0];
    const float* feat    = (const float*)d_in[1];
    const float* w_f1    = (const float*)d_in[2];
    const float* w_f2    = (const float*)d_in[3];
    const float* w_pre0  = (const float*)d_in[4];
    const float* w_pre1  = (const float*)d_in[5];
    const float* w_a0    = (const float*)d_in[6];
    const float* w_a1    = (const float*)d_in[7];
    const float* w_b0    = (const float*)d_in[8];
    const float* w_b1    = (const float*)d_in[9];
    const int* src_idx   = (const int*)d_in[10];
    const int* edge_mask = (const int*)d_in[11];
    float* out = (float*)d_out;

    float* pre_t = (float*)d_ws;                              // 4 MB
    short* w1t_g = (short*)((char*)d_ws + (size_t)4194304);   // 4 KB
    short* w2t_g = w1t_g + 64 * 32;                           // 8 KB

    pre_kernel<<<NN / 8, 256, 0, stream>>>(feat, w_pre0, w_pre1, pre_t,
                                           w_f1, w_f2, w1t_g, w2t_g);
    edge_kernel<<<NN / 2, 256, 0, stream>>>(xyz, feat, pre_t, w1t_g, w2t_g,
                                            w_a0, w_a1, w_b0, w_b1,
                                            src_idx, edge_mask, out);
}